// Round 10
// baseline (637.357 us; speedup 1.0000x reference)
//
#include <hip/hip_runtime.h>
#include <hip/hip_bf16.h>
#include <math.h>

#define D 128

typedef __attribute__((ext_vector_type(4))) float f32x4;
typedef __attribute__((ext_vector_type(8))) short bf16x8;

__device__ inline unsigned short f2bf(float f){
  unsigned u = __float_as_uint(f);
  u += 0x7fffu + ((u >> 16) & 1u);
  return (unsigned short)(u >> 16);
}
__device__ inline float wred_sum(float v){
#pragma unroll
  for (int m = 1; m < 64; m <<= 1) v += __shfl_xor(v, m, 64);
  return v;
}
__device__ inline float wred_max(float v){
#pragma unroll
  for (int m = 1; m < 64; m <<= 1) v = fmaxf(v, __shfl_xor(v, m, 64));
  return v;
}

// ---- embedding mean-pool: wave per node; padding is suffix-only ----
__global__ __launch_bounds__(256) void k_pool(const int* __restrict__ xpad,
    const float* __restrict__ emb, float* __restrict__ xo, int N, int M){
  int wv = threadIdx.x >> 6, ln = threadIdx.x & 63;
  int n = blockIdx.x * 4 + wv;
  if (n >= N) return;
  int cnt = 0;
  while (cnt < M && xpad[n * M + cnt] >= 0) ++cnt;
  float2 acc = {0.f, 0.f};
  int m = 0;
  for (; m + 1 < cnt; m += 2){
    int i0 = xpad[n * M + m], i1 = xpad[n * M + m + 1];
    float2 v0 = ((const float2*)(emb + (size_t)i0 * D))[ln];
    float2 v1 = ((const float2*)(emb + (size_t)i1 * D))[ln];
    acc.x += v0.x + v1.x; acc.y += v0.y + v1.y;
  }
  if (m < cnt){
    int i0 = xpad[n * M + m];
    float2 v0 = ((const float2*)(emb + (size_t)i0 * D))[ln];
    acc.x += v0.x; acc.y += v0.y;
  }
  float inv = 1.f / (float)cnt;
  float2 o; o.x = acc.x * inv; o.y = acc.y * inv;
  ((float2*)(xo + (size_t)n * D))[ln] = o;
}

// ---- CSR build over buckets (dst*R + et) ----
__global__ void k_count(const int* __restrict__ dst, const int* __restrict__ et,
                        int* __restrict__ cnt, int E, int R){
  int e = blockIdx.x * 256 + threadIdx.x;
  if (e < E) atomicAdd(&cnt[dst[e] * R + et[e]], 1);
}

// ---- hierarchical exclusive scan over nb buckets (1024 elems / block) ----
__global__ __launch_bounds__(256) void k_scan_blk(const int* __restrict__ cc,
    int* __restrict__ bsum, int nb){
  __shared__ int sh[256];
  int base = blockIdx.x * 1024 + threadIdx.x * 4;
  int s = 0;
#pragma unroll
  for (int j = 0; j < 4; ++j){
    int i = base + j;
    if (i < nb) s += cc[i];
  }
  sh[threadIdx.x] = s; __syncthreads();
  for (int off = 128; off > 0; off >>= 1){
    if (threadIdx.x < off) sh[threadIdx.x] += sh[threadIdx.x + off];
    __syncthreads();
  }
  if (threadIdx.x == 0) bsum[blockIdx.x] = sh[0];
}

__global__ __launch_bounds__(1024) void k_scan_top(const int* __restrict__ bsum,
    int* __restrict__ boff, int* __restrict__ rp, int nblk, int nb){
  __shared__ int sh[1024];
  int t = threadIdx.x;
  int v = (t < nblk) ? bsum[t] : 0;
  sh[t] = v; __syncthreads();
  for (int off = 1; off < 1024; off <<= 1){
    int a = sh[t];
    int b = (t >= off) ? sh[t - off] : 0;
    __syncthreads();
    sh[t] = a + b;
    __syncthreads();
  }
  if (t < nblk) boff[t] = sh[t] - v;       // exclusive
  if (t == 1023) rp[nb] = sh[1023];        // total
}

__global__ __launch_bounds__(256) void k_scan_fin(int* __restrict__ cc,
    const int* __restrict__ boff, int* __restrict__ rp, int nb){
  __shared__ int sh[256];
  int t = threadIdx.x;
  int base = blockIdx.x * 1024 + t * 4;
  int c[4]; int local = 0;
#pragma unroll
  for (int j = 0; j < 4; ++j){
    int i = base + j;
    c[j] = (i < nb) ? cc[i] : 0;
    local += c[j];
  }
  sh[t] = local; __syncthreads();
  for (int off = 1; off < 256; off <<= 1){
    int a = sh[t];
    int b = (t >= off) ? sh[t - off] : 0;
    __syncthreads();
    sh[t] = a + b;
    __syncthreads();
  }
  int run = sh[t] - local + boff[blockIdx.x];
#pragma unroll
  for (int j = 0; j < 4; ++j){
    int i = base + j;
    if (i < nb){ rp[i] = run; cc[i] = run; run += c[j]; }
  }
}

__global__ void k_scatter(const int* __restrict__ src, const int* __restrict__ dst,
    const int* __restrict__ et, int* __restrict__ cur, int* __restrict__ pack, int E, int R){
  int e = blockIdx.x * 256 + threadIdx.x;
  if (e < E){
    int t = et[e];
    int p = atomicAdd(&cur[dst[e] * R + t], 1);
    pack[p] = (t << 27) | src[e];
  }
}

// ---- wq[r][d] = sum_h w[r][d][h]*q[h]; wk likewise ----
__global__ void k_wqk(const float* __restrict__ w, const float* __restrict__ q,
    const float* __restrict__ kk, float* __restrict__ wq, float* __restrict__ wk, int RD){
  int id = blockIdx.x * 256 + threadIdx.x;
  if (id >= RD) return;
  const float* wr = w + (size_t)id * D;
  float sq = 0.f, sk = 0.f;
  for (int h = 0; h < D; ++h){ float v = wr[h]; sq += v * q[h]; sk += v * kk[h]; }
  wq[id] = sq; wk[id] = sk;
}

// ---- w[r][d][h] fp32 -> wbf[r][h][d] bf16 (transposed) ----
__global__ void k_wtr(const float* __restrict__ w, unsigned short* __restrict__ wbf, int total){
  int id = blockIdx.x * 256 + threadIdx.x;
  if (id >= total) return;
  int d = id & 127, h = (id >> 7) & 127, r = id >> 14;
  wbf[id] = f2bf(w[(size_t)r * 16384 + d * 128 + h]);
}

// ---- plain fp32 -> bf16 convert (no transpose) ----
__global__ void k_cvt(const float* __restrict__ s, unsigned short* __restrict__ dd, int total){
  int id = blockIdx.x * 256 + threadIdx.x;
  if (id < total) dd[id] = f2bf(s[id]);
}

// ---- a[n,r]=x[n].wq[r], b[n,r]=x[n].wk[r]: wave per node ----
__global__ __launch_bounds__(256) void k_ab(const float* __restrict__ x,
    const float* __restrict__ wq, const float* __restrict__ wk,
    float* __restrict__ aT, float* __restrict__ bT, int N, int R){
  __shared__ float lq[8 * D], lk[8 * D];
  for (int i = threadIdx.x; i < R * D; i += 256){ lq[i] = wq[i]; lk[i] = wk[i]; }
  __syncthreads();
  int wv = threadIdx.x >> 6, ln = threadIdx.x & 63;
  int n = blockIdx.x * 4 + wv;
  if (n >= N) return;
  float2 xv = ((const float2*)(x + (size_t)n * D))[ln];
  for (int r = 0; r < R; ++r){
    float pa = xv.x * lq[r * D + 2 * ln] + xv.y * lq[r * D + 2 * ln + 1];
    float pb = xv.x * lk[r * D + 2 * ln] + xv.y * lk[r * D + 2 * ln + 1];
    pa = wred_sum(pa); pb = wred_sum(pb);
    if (ln == 0){ aT[n * R + r] = pa; bT[n * R + r] = pb; }
  }
}

// ---- segment softmax over dst: wave per node ----
__global__ __launch_bounds__(256) void k_alpha(const int* __restrict__ rp,
    const int* __restrict__ pack, const float* __restrict__ aT, const float* __restrict__ bT,
    float* __restrict__ alp, int N, int R){
  int wv = threadIdx.x >> 6, ln = threadIdx.x & 63;
  int n = blockIdx.x * 4 + wv;
  if (n >= N) return;
  int beg = rp[n * R], end = rp[n * R + R];
  if (end <= beg) return;
  float mx = -3.4e38f;
  for (int i = beg + ln; i < end; i += 64){
    int v = pack[i]; int t = v >> 27; int s = v & 0x7ffffff;
    float l = aT[n * R + t] + bT[s * R + t];
    l = l > 0.f ? l : 0.2f * l;
    mx = fmaxf(mx, l);
  }
  mx = wred_max(mx);
  float sm = 0.f;
  for (int i = beg + ln; i < end; i += 64){
    int v = pack[i]; int t = v >> 27; int s = v & 0x7ffffff;
    float l = aT[n * R + t] + bT[s * R + t];
    l = l > 0.f ? l : 0.2f * l;
    float ev = __expf(l - mx);
    alp[i] = ev; sm += ev;
  }
  sm = wred_sum(sm);
  float inv = 1.f / sm;
  for (int i = beg + ln; i < end; i += 64) alp[i] *= inv;
}

// ---- xw[r][n][h] = (x[n] @ w[r])[h], bf16, via MFMA.
//      [R][N][128] LAYOUT: a (tile,r) block's 64 rows are CONTIGUOUS ->
//      one 16KB streaming write burst (R5-R9: the 2KB-strided 256B segments
//      of [N][R*128] paced every variant at ~0.83 TB/s write).
//      One (tile,r) per block + bijective XCD swizzle for x L2 reuse. ----
__global__ __launch_bounds__(256) void k_xw(const float* __restrict__ x,
    const unsigned short* __restrict__ wbf,  // [R][h][k] bf16
    unsigned short* __restrict__ xw,         // [R][N][128] bf16
    int N, int R, int nwg){
  __shared__ unsigned short ot[64][136];     // 272B rows (17x16B): uint4-aligned
  int wv = threadIdx.x >> 6, ln = threadIdx.x & 63;
  int g = ln >> 4, m16 = ln & 15;
  // bijective chunked swizzle: hw XCD = orig % 8
  int orig = blockIdx.x;
  int q = nwg >> 3, rm = nwg & 7;
  int xcd = orig & 7, idx = orig >> 3;
  int wgid = (xcd < rm ? xcd * (q + 1) : rm * (q + 1) + (xcd - rm) * q) + idx;
  int r    = wgid % 8;                       // R == 8; 8 r-blocks/tile share one XCD
  int tile = wgid / 8;
  int n0 = tile * 64;
  int nA = n0 + wv * 16 + m16;
  bf16x8 af[4];
#pragma unroll
  for (int kc = 0; kc < 4; ++kc){
    float4 a0 = {0.f,0.f,0.f,0.f}, a1 = {0.f,0.f,0.f,0.f};
    if (nA < N){
      const float* ap = x + (size_t)nA * D + kc * 32 + g * 8;
      a0 = *(const float4*)ap; a1 = *(const float4*)(ap + 4);
    }
    af[kc][0] = (short)f2bf(a0.x); af[kc][1] = (short)f2bf(a0.y);
    af[kc][2] = (short)f2bf(a0.z); af[kc][3] = (short)f2bf(a0.w);
    af[kc][4] = (short)f2bf(a1.x); af[kc][5] = (short)f2bf(a1.y);
    af[kc][6] = (short)f2bf(a1.z); af[kc][7] = (short)f2bf(a1.w);
  }
  f32x4 acc[8];
#pragma unroll
  for (int i = 0; i < 8; ++i) acc[i] = (f32x4){0.f, 0.f, 0.f, 0.f};
  const unsigned short* wr = wbf + (size_t)r * 16384;
#pragma unroll
  for (int kc = 0; kc < 4; ++kc){
#pragma unroll
    for (int hf = 0; hf < 8; ++hf){
      bf16x8 bfr = *(const bf16x8*)(wr + (hf * 16 + m16) * 128 + kc * 32 + g * 8);
      acc[hf] = __builtin_amdgcn_mfma_f32_16x16x32_bf16(af[kc], bfr, acc[hf], 0, 0, 0);
    }
  }
#pragma unroll
  for (int hf = 0; hf < 8; ++hf){
#pragma unroll
    for (int jj = 0; jj < 4; ++jj){
      ot[wv * 16 + g * 4 + jj][hf * 16 + m16] = f2bf(acc[hf][jj]);
    }
  }
  __syncthreads();
  // streaming write: 1024 x uint4 over a CONTIGUOUS 16KB span of xw[r]
  unsigned short* dst = xw + ((size_t)r * N + n0) * 128;
  int limit = (N - n0 < 64) ? (N - n0) * 16 : 1024;
  for (int i = threadIdx.x; i < limit; i += 256){
    int row = i >> 4, c16 = i & 15;
    *(uint4*)(dst + row * 128 + c16 * 8) = *(const uint4*)&ot[row][c16 * 8];
  }
}

// ---- aggregation: one wave per node, 4-wide edge unroll for MLP ----
__global__ __launch_bounds__(256) void k_aggX(const unsigned short* __restrict__ xw,
    const int* __restrict__ rp, const int* __restrict__ pack, const float* __restrict__ alp,
    const float* __restrict__ bias, float* __restrict__ xo, int N, int R){
  int wv = threadIdx.x >> 6, ln = threadIdx.x & 63;
  int n = blockIdx.x * 4 + wv;
  if (n >= N) return;
  int beg = rp[n * R], end = rp[n * R + R];
  float2 s0 = {0.f, 0.f}, s1 = {0.f, 0.f}, s2 = {0.f, 0.f}, s3 = {0.f, 0.f};
  int i = beg;
  for (; i + 3 < end; i += 4){
    int v0 = pack[i], v1 = pack[i + 1], v2 = pack[i + 2], v3 = pack[i + 3];
    float al0 = alp[i], al1 = alp[i + 1], al2 = alp[i + 2], al3 = alp[i + 3];
    unsigned u0 = *(const unsigned*)(xw + ((size_t)(v0 >> 27) * N + (v0 & 0x7ffffff)) * 128 + 2 * ln);
    unsigned u1 = *(const unsigned*)(xw + ((size_t)(v1 >> 27) * N + (v1 & 0x7ffffff)) * 128 + 2 * ln);
    unsigned u2 = *(const unsigned*)(xw + ((size_t)(v2 >> 27) * N + (v2 & 0x7ffffff)) * 128 + 2 * ln);
    unsigned u3 = *(const unsigned*)(xw + ((size_t)(v3 >> 27) * N + (v3 & 0x7ffffff)) * 128 + 2 * ln);
    s0.x += al0 * __uint_as_float(u0 << 16);
    s0.y += al0 * __uint_as_float(u0 & 0xffff0000u);
    s1.x += al1 * __uint_as_float(u1 << 16);
    s1.y += al1 * __uint_as_float(u1 & 0xffff0000u);
    s2.x += al2 * __uint_as_float(u2 << 16);
    s2.y += al2 * __uint_as_float(u2 & 0xffff0000u);
    s3.x += al3 * __uint_as_float(u3 << 16);
    s3.y += al3 * __uint_as_float(u3 & 0xffff0000u);
  }
  for (; i < end; ++i){
    int v0 = pack[i];
    float al0 = alp[i];
    unsigned u0 = *(const unsigned*)(xw + ((size_t)(v0 >> 27) * N + (v0 & 0x7ffffff)) * 128 + 2 * ln);
    s0.x += al0 * __uint_as_float(u0 << 16);
    s0.y += al0 * __uint_as_float(u0 & 0xffff0000u);
  }
  float2 o;
  o.x = fmaxf(s0.x + s1.x + s2.x + s3.x + bias[2 * ln], 0.f);
  o.y = fmaxf(s0.y + s1.y + s2.y + s3.y + bias[2 * ln + 1], 0.f);
  ((float2*)(xo + (size_t)n * D))[ln] = o;
}

// ---- fallback: fused aggregate (S-tile in LDS) + MFMA GEMM + bias + relu ----
__global__ __launch_bounds__(256) void k_agg(const float* __restrict__ x_in,
    const unsigned short* __restrict__ wbf, const float* __restrict__ bias,
    const int* __restrict__ rp, const int* __restrict__ pack,
    const float* __restrict__ alp, float* __restrict__ x_out, int N, int R){
  __shared__ float st[64][132];
  __shared__ unsigned short wt[128][136];
  int wv = threadIdx.x >> 6, ln = threadIdx.x & 63;
  int g = ln >> 4, m16 = ln & 15;
  int n0 = blockIdx.x * 64;
  f32x4 acc[8];
#pragma unroll
  for (int i = 0; i < 8; ++i) acc[i] = (f32x4){0.f, 0.f, 0.f, 0.f};

  for (int r = 0; r < R; ++r){
    __syncthreads();
    {
      const uint4* src = (const uint4*)(wbf + (size_t)r * 16384);
      for (int i = threadIdx.x; i < 2048; i += 256){
        int h = i >> 4, dblk = i & 15;
        *(uint4*)&wt[h][dblk * 8] = src[i];
      }
    }
    for (int j = 0; j < 16; ++j){
      int n = n0 + wv * 16 + j;
      float2 s2 = {0.f, 0.f};
      if (n < N){
        int beg = rp[n * R + r], end = rp[n * R + r + 1];
        for (int i = beg; i < end; ++i){
          int s = pack[i] & 0x7ffffff;
          float al = alp[i];
          float2 xv = ((const float2*)(x_in + (size_t)s * D))[ln];
          s2.x += al * xv.x; s2.y += al * xv.y;
        }
      }
      *(float2*)&st[wv * 16 + j][2 * ln] = s2;
    }
    __syncthreads();
#pragma unroll
    for (int kc = 0; kc < 4; ++kc){
      const float* ap = &st[wv * 16 + m16][kc * 32 + g * 8];
      float4 a0 = *(const float4*)ap;
      float4 a1 = *(const float4*)(ap + 4);
      bf16x8 af;
      af[0] = (short)f2bf(a0.x); af[1] = (short)f2bf(a0.y);
      af[2] = (short)f2bf(a0.z); af[3] = (short)f2bf(a0.w);
      af[4] = (short)f2bf(a1.x); af[5] = (short)f2bf(a1.y);
      af[6] = (short)f2bf(a1.z); af[7] = (short)f2bf(a1.w);
#pragma unroll
      for (int hf = 0; hf < 8; ++hf){
        bf16x8 bfr = *(const bf16x8*)&wt[hf * 16 + m16][kc * 32 + g * 8];
        acc[hf] = __builtin_amdgcn_mfma_f32_16x16x32_bf16(af, bfr, acc[hf], 0, 0, 0);
      }
    }
  }
#pragma unroll
  for (int hf = 0; hf < 8; ++hf){
    int h = hf * 16 + m16;
    float bv = bias[h];
#pragma unroll
    for (int jj = 0; jj < 4; ++jj){
      int n = n0 + wv * 16 + g * 4 + jj;
      if (n < N){
        float v = acc[hf][jj] + bv;
        x_out[(size_t)n * D + h] = fmaxf(v, 0.f);
      }
    }
  }
}

// ---- final linear + per-graph segment sum: LDS per-block reduce over sorted
// batch runs, then ONE atomicAdd per (graph,h) run present in the tile ----
__global__ __launch_bounds__(256) void k_final(const float* __restrict__ x,
    const unsigned short* __restrict__ lwbf, const float* __restrict__ lb,
    const int* __restrict__ batch, float* __restrict__ out, int N){
  __shared__ unsigned short wt[128][136]; // lin_w [h][k] bf16
  __shared__ float st[64][129];           // per-node output rows
  __shared__ int bsh[64];
  {
    const uint4* src = (const uint4*)lwbf;
    for (int i = threadIdx.x; i < 2048; i += 256){
      int h = i >> 4, kblk = i & 15;
      *(uint4*)&wt[h][kblk * 8] = src[i];
    }
  }
  __syncthreads();
  int wv = threadIdx.x >> 6, ln = threadIdx.x & 63;
  int g = ln >> 4, m16 = ln & 15;
  int n0 = blockIdx.x * 64;
  f32x4 acc[8];
#pragma unroll
  for (int i = 0; i < 8; ++i) acc[i] = (f32x4){0.f, 0.f, 0.f, 0.f};
#pragma unroll
  for (int kc = 0; kc < 4; ++kc){
    int nA = n0 + wv * 16 + m16;
    float4 a0 = {0.f,0.f,0.f,0.f}, a1 = {0.f,0.f,0.f,0.f};
    if (nA < N){
      const float* ap = x + (size_t)nA * D + kc * 32 + g * 8;
      a0 = *(const float4*)ap; a1 = *(const float4*)(ap + 4);
    }
    bf16x8 af;
    af[0] = (short)f2bf(a0.x); af[1] = (short)f2bf(a0.y);
    af[2] = (short)f2bf(a0.z); af[3] = (short)f2bf(a0.w);
    af[4] = (short)f2bf(a1.x); af[5] = (short)f2bf(a1.y);
    af[6] = (short)f2bf(a1.z); af[7] = (short)f2bf(a1.w);
#pragma unroll
    for (int hf = 0; hf < 8; ++hf){
      bf16x8 bfr = *(const bf16x8*)&wt[hf * 16 + m16][kc * 32 + g * 8];
      acc[hf] = __builtin_amdgcn_mfma_f32_16x16x32_bf16(af, bfr, acc[hf], 0, 0, 0);
    }
  }
  // rows -> LDS (per-node bias added here; invalid rows zeroed)
#pragma unroll
  for (int hf = 0; hf < 8; ++hf){
    int h = hf * 16 + m16;
    float bv = lb[h];
#pragma unroll
    for (int jj = 0; jj < 4; ++jj){
      int row = wv * 16 + g * 4 + jj;
      int n = n0 + row;
      st[row][h] = (n < N) ? (acc[hf][jj] + bv) : 0.f;
    }
  }
  if (threadIdx.x < 64){
    int n = n0 + threadIdx.x;
    bsh[threadIdx.x] = (n < N) ? batch[n] : -1;
  }
  __syncthreads();
  // scan sorted rows, one atomic per (graph,h) run
  if (threadIdx.x < 128){
    int h = threadIdx.x;
    int lastValid = (N - n0 < 64) ? (N - n0 - 1) : 63;
    int cg = bsh[0];
    float sum = 0.f;
    for (int row = 0; row <= lastValid; ++row){
      int bg = bsh[row];
      if (bg != cg){
        atomicAdd(&out[(size_t)cg * D + h], sum);
        sum = 0.f; cg = bg;
      }
      sum += st[row][h];
    }
    atomicAdd(&out[(size_t)cg * D + h], sum);
  }
}

extern "C" void kernel_launch(void* const* d_in, const int* in_sizes, int n_in,
                              void* d_out, int out_size, void* d_ws, size_t ws_size,
                              hipStream_t stream){
  const int*   xpad  = (const int*)d_in[0];
  const int*   eidx  = (const int*)d_in[1];
  const int*   etyp  = (const int*)d_in[2];
  const int*   batch = (const int*)d_in[3];
  const float* emb   = (const float*)d_in[4];
  const float* w1    = (const float*)d_in[5];
  const float* q1    = (const float*)d_in[6];
  const float* k1    = (const float*)d_in[7];
  const float* b1    = (const float*)d_in[8];
  const float* w2    = (const float*)d_in[9];
  const float* q2    = (const float*)d_in[10];
  const float* k2    = (const float*)d_in[11];
  const float* b2    = (const float*)d_in[12];
  const float* lw    = (const float*)d_in[13];
  const float* lb    = (const float*)d_in[14];

  int N = in_sizes[3];
  int M = in_sizes[0] / N;
  int E = in_sizes[2];
  int R = in_sizes[5] / (128 * 128);
  int NB = N * R;
  const int* esrc = eidx;
  const int* edst = eidx + E;

  char* p = (char*)d_ws;
  auto carve = [&](size_t b) -> void* {
    void* q = (void*)p; p += (b + 255) & ~(size_t)255; return q;
  };
  float* x_a  = (float*)carve((size_t)N * D * 4);
  float* x_b  = (float*)carve((size_t)N * D * 4);
  float* wq1  = (float*)carve((size_t)R * D * 4);
  float* wk1  = (float*)carve((size_t)R * D * 4);
  float* wq2  = (float*)carve((size_t)R * D * 4);
  float* wk2  = (float*)carve((size_t)R * D * 4);
  float* aT   = (float*)carve((size_t)N * R * 4);
  float* bT   = (float*)carve((size_t)N * R * 4);
  int*   rp   = (int*)carve((size_t)(NB + 1) * 4);
  int*   cur  = (int*)carve((size_t)NB * 4);
  int*   pack = (int*)carve((size_t)E * 4);
  float* alp  = (float*)carve((size_t)E * 4);
  unsigned short* wbf1 = (unsigned short*)carve((size_t)R * 128 * 128 * 2);
  unsigned short* wbf2 = (unsigned short*)carve((size_t)R * 128 * 128 * 2);
  unsigned short* lwbf = (unsigned short*)carve((size_t)128 * 128 * 2);
  int* bsum = (int*)carve((size_t)4096 * 4);
  int* boff = (int*)carve((size_t)4096 * 4);
  if ((size_t)(p - (char*)d_ws) > ws_size) return;  // base ws too small: fail visibly
  unsigned short* xw = (unsigned short*)carve((size_t)N * R * 128 * 2);
  bool use_xw = ((size_t)(p - (char*)d_ws) <= ws_size);

  hipMemsetAsync(cur, 0, (size_t)NB * 4, stream);
  hipMemsetAsync(d_out, 0, (size_t)out_size * 4, stream);

  int eg = (E + 255) / 256;
  int nblk = (NB + 1023) / 1024;
  k_count   <<<eg, 256, 0, stream>>>(edst, etyp, cur, E, R);
  k_scan_blk<<<nblk, 256, 0, stream>>>(cur, bsum, NB);
  k_scan_top<<<1, 1024, 0, stream>>>(bsum, boff, rp, nblk, NB);
  k_scan_fin<<<nblk, 256, 0, stream>>>(cur, boff, rp, NB);
  k_scatter <<<eg, 256, 0, stream>>>(esrc, edst, etyp, cur, pack, E, R);

  k_wqk<<<(R * D + 255) / 256, 256, 0, stream>>>(w1, q1, k1, wq1, wk1, R * D);
  k_wqk<<<(R * D + 255) / 256, 256, 0, stream>>>(w2, q2, k2, wq2, wk2, R * D);
  int wtot = R * 128 * 128;
  k_wtr<<<(wtot + 255) / 256, 256, 0, stream>>>(w1, wbf1, wtot);
  k_wtr<<<(wtot + 255) / 256, 256, 0, stream>>>(w2, wbf2, wtot);
  k_cvt<<<(128 * 128 + 255) / 256, 256, 0, stream>>>(lw, lwbf, 128 * 128);

  int ng4 = (N + 3) / 4;
  int ntile = (N + 63) / 64;
  int nwg = ntile * R;
  k_pool<<<ng4, 256, 0, stream>>>(xpad, emb, x_a, N, M);

  // layer 1
  k_ab   <<<ng4, 256, 0, stream>>>(x_a, wq1, wk1, aT, bT, N, R);
  k_alpha<<<ng4, 256, 0, stream>>>(rp, pack, aT, bT, alp, N, R);
  if (use_xw){
    k_xw  <<<nwg, 256, 0, stream>>>(x_a, wbf1, xw, N, R, nwg);
    k_aggX<<<ng4, 256, 0, stream>>>(xw, rp, pack, alp, b1, x_b, N, R);
  } else {
    k_agg <<<ntile, 256, 0, stream>>>(x_a, wbf1, b1, rp, pack, alp, x_b, N, R);
  }

  // layer 2
  k_ab   <<<ng4, 256, 0, stream>>>(x_b, wq2, wk2, aT, bT, N, R);
  k_alpha<<<ng4, 256, 0, stream>>>(rp, pack, aT, bT, alp, N, R);
  if (use_xw){
    k_xw  <<<nwg, 256, 0, stream>>>(x_b, wbf2, xw, N, R, nwg);
    k_aggX<<<ng4, 256, 0, stream>>>(xw, rp, pack, alp, b2, x_a, N, R);
  } else {
    k_agg <<<ntile, 256, 0, stream>>>(x_b, wbf2, b2, rp, pack, alp, x_a, N, R);
  }

  // final linear + graph segment-sum
  k_final<<<ntile, 256, 0, stream>>>(x_a, lwbf, lb, batch, (float*)d_out, N);
}

// Round 11
// 478.819 us; speedup vs baseline: 1.3311x; 1.3311x over previous
//
#include <hip/hip_runtime.h>
#include <hip/hip_bf16.h>
#include <math.h>

#define D 128

typedef __attribute__((ext_vector_type(4))) float f32x4;
typedef __attribute__((ext_vector_type(8))) short bf16x8;

__device__ inline unsigned short f2bf(float f){
  unsigned u = __float_as_uint(f);
  u += 0x7fffu + ((u >> 16) & 1u);
  return (unsigned short)(u >> 16);
}
__device__ inline float bf2f(unsigned short u){
  return __uint_as_float((unsigned)u << 16);
}
__device__ inline float wred_sum(float v){
#pragma unroll
  for (int m = 1; m < 64; m <<= 1) v += __shfl_xor(v, m, 64);
  return v;
}
__device__ inline float wred_max(float v){
#pragma unroll
  for (int m = 1; m < 64; m <<= 1) v = fmaxf(v, __shfl_xor(v, m, 64));
  return v;
}

// ---- embedding mean-pool: wave per node -> x bf16 ----
__global__ __launch_bounds__(256) void k_pool(const int* __restrict__ xpad,
    const float* __restrict__ emb, unsigned short* __restrict__ xo, int N, int M){
  int wv = threadIdx.x >> 6, ln = threadIdx.x & 63;
  int n = blockIdx.x * 4 + wv;
  if (n >= N) return;
  // vectorized valid count (padding is suffix-only; M == 8)
  const int4* xr = (const int4*)(xpad + n * M);
  int4 ia = xr[0], ib = xr[1];
  int cnt = (ia.x >= 0) + (ia.y >= 0) + (ia.z >= 0) + (ia.w >= 0)
          + (ib.x >= 0) + (ib.y >= 0) + (ib.z >= 0) + (ib.w >= 0);
  float2 acc = {0.f, 0.f};
  int m = 0;
  for (; m + 1 < cnt; m += 2){
    int i0 = xpad[n * M + m], i1 = xpad[n * M + m + 1];
    float2 v0 = ((const float2*)(emb + (size_t)i0 * D))[ln];
    float2 v1 = ((const float2*)(emb + (size_t)i1 * D))[ln];
    acc.x += v0.x + v1.x; acc.y += v0.y + v1.y;
  }
  if (m < cnt){
    int i0 = xpad[n * M + m];
    float2 v0 = ((const float2*)(emb + (size_t)i0 * D))[ln];
    acc.x += v0.x; acc.y += v0.y;
  }
  float inv = 1.f / (float)cnt;
  unsigned u = ((unsigned)f2bf(acc.y * inv) << 16) | f2bf(acc.x * inv);
  *(unsigned*)(xo + (size_t)n * D + 2 * ln) = u;
}

// ---- CSR build over buckets (dst*R + et) ----
__global__ void k_count(const int* __restrict__ dst, const int* __restrict__ et,
                        int* __restrict__ cnt, int E, int R){
  int e = blockIdx.x * 256 + threadIdx.x;
  if (e < E) atomicAdd(&cnt[dst[e] * R + et[e]], 1);
}

__global__ __launch_bounds__(256) void k_scan_blk(const int* __restrict__ cc,
    int* __restrict__ bsum, int nb){
  __shared__ int sh[256];
  int base = blockIdx.x * 1024 + threadIdx.x * 4;
  int s = 0;
#pragma unroll
  for (int j = 0; j < 4; ++j){
    int i = base + j;
    if (i < nb) s += cc[i];
  }
  sh[threadIdx.x] = s; __syncthreads();
  for (int off = 128; off > 0; off >>= 1){
    if (threadIdx.x < off) sh[threadIdx.x] += sh[threadIdx.x + off];
    __syncthreads();
  }
  if (threadIdx.x == 0) bsum[blockIdx.x] = sh[0];
}

__global__ __launch_bounds__(1024) void k_scan_top(const int* __restrict__ bsum,
    int* __restrict__ boff, int* __restrict__ rp, int nblk, int nb){
  __shared__ int sh[1024];
  int t = threadIdx.x;
  int v = (t < nblk) ? bsum[t] : 0;
  sh[t] = v; __syncthreads();
  for (int off = 1; off < 1024; off <<= 1){
    int a = sh[t];
    int b = (t >= off) ? sh[t - off] : 0;
    __syncthreads();
    sh[t] = a + b;
    __syncthreads();
  }
  if (t < nblk) boff[t] = sh[t] - v;
  if (t == 1023) rp[nb] = sh[1023];
}

__global__ __launch_bounds__(256) void k_scan_fin(int* __restrict__ cc,
    const int* __restrict__ boff, int* __restrict__ rp, int nb){
  __shared__ int sh[256];
  int t = threadIdx.x;
  int base = blockIdx.x * 1024 + t * 4;
  int c[4]; int local = 0;
#pragma unroll
  for (int j = 0; j < 4; ++j){
    int i = base + j;
    c[j] = (i < nb) ? cc[i] : 0;
    local += c[j];
  }
  sh[t] = local; __syncthreads();
  for (int off = 1; off < 256; off <<= 1){
    int a = sh[t];
    int b = (t >= off) ? sh[t - off] : 0;
    __syncthreads();
    sh[t] = a + b;
    __syncthreads();
  }
  int run = sh[t] - local + boff[blockIdx.x];
#pragma unroll
  for (int j = 0; j < 4; ++j){
    int i = base + j;
    if (i < nb){ rp[i] = run; cc[i] = run; run += c[j]; }
  }
}

__global__ void k_scatter(const int* __restrict__ src, const int* __restrict__ dst,
    const int* __restrict__ et, int* __restrict__ cur, int* __restrict__ pack, int E, int R){
  int e = blockIdx.x * 256 + threadIdx.x;
  if (e < E){
    int t = et[e];
    int p = atomicAdd(&cur[dst[e] * R + t], 1);
    pack[p] = (t << 27) | src[e];
  }
}

// ---- w[r][d][h] fp32 -> wbf[r][h][d] bf16 (transposed) ----
__global__ void k_wtr(const float* __restrict__ w, unsigned short* __restrict__ wbf, int total){
  int id = blockIdx.x * 256 + threadIdx.x;
  if (id >= total) return;
  int d = id & 127, h = (id >> 7) & 127, r = id >> 14;
  wbf[id] = f2bf(w[(size_t)r * 16384 + d * 128 + h]);
}

__global__ void k_cvt(const float* __restrict__ s, unsigned short* __restrict__ dd, int total){
  int id = blockIdx.x * 256 + threadIdx.x;
  if (id < total) dd[id] = f2bf(s[id]);
}

// ---- xw[r][n][h] = (x[n] @ w[r])[h] bf16 via MFMA, one (tile,r)/block,
//      XCD swizzle for x L2 reuse. FUSED: a[n,r] = xw[n,r,:]@q and
//      b[n,r] = xw[n,r,:]@k computed from the accumulators (kills k_ab/k_wqk):
//      in-lane sum over hf, then 16-lane butterfly over m16. ----
__global__ __launch_bounds__(256) void k_xw(const unsigned short* __restrict__ x,
    const unsigned short* __restrict__ wbf,  // [R][h][k] bf16
    const float* __restrict__ qv, const float* __restrict__ kv,  // [128]
    unsigned short* __restrict__ xw,         // [R][N][128] bf16
    float* __restrict__ aT, float* __restrict__ bT,              // [N*R]
    int N, int R, int nwg){
  __shared__ unsigned short ot[64][136];
  int wv = threadIdx.x >> 6, ln = threadIdx.x & 63;
  int g = ln >> 4, m16 = ln & 15;
  int orig = blockIdx.x;
  int q = nwg >> 3, rm = nwg & 7;
  int xcd = orig & 7, idx = orig >> 3;
  int wgid = (xcd < rm ? xcd * (q + 1) : rm * (q + 1) + (xcd - rm) * q) + idx;
  int r    = wgid % 8;
  int tile = wgid / 8;
  int n0 = tile * 64;
  int nA = n0 + wv * 16 + m16;
  bf16x8 af[4];
#pragma unroll
  for (int kc = 0; kc < 4; ++kc) af[kc] = (bf16x8){0,0,0,0,0,0,0,0};
  if (nA < N){
#pragma unroll
    for (int kc = 0; kc < 4; ++kc)
      af[kc] = *(const bf16x8*)(x + (size_t)nA * D + kc * 32 + g * 8);
  }
  f32x4 acc[8];
#pragma unroll
  for (int i = 0; i < 8; ++i) acc[i] = (f32x4){0.f, 0.f, 0.f, 0.f};
  const unsigned short* wr = wbf + (size_t)r * 16384;
#pragma unroll
  for (int kc = 0; kc < 4; ++kc){
#pragma unroll
    for (int hf = 0; hf < 8; ++hf){
      bf16x8 bfr = *(const bf16x8*)(wr + (hf * 16 + m16) * 128 + kc * 32 + g * 8);
      acc[hf] = __builtin_amdgcn_mfma_f32_16x16x32_bf16(af[kc], bfr, acc[hf], 0, 0, 0);
    }
  }
  // fused a,b: lane holds h = hf*16+m16 for rows (wv*16 + g*4 + jj)
  {
    float qr[8], kr[8];
#pragma unroll
    for (int hf = 0; hf < 8; ++hf){ qr[hf] = qv[hf * 16 + m16]; kr[hf] = kv[hf * 16 + m16]; }
#pragma unroll
    for (int jj = 0; jj < 4; ++jj){
      float pa = 0.f, pb = 0.f;
#pragma unroll
      for (int hf = 0; hf < 8; ++hf){
        pa += acc[hf][jj] * qr[hf];
        pb += acc[hf][jj] * kr[hf];
      }
#pragma unroll
      for (int mm = 1; mm < 16; mm <<= 1){
        pa += __shfl_xor(pa, mm, 64);
        pb += __shfl_xor(pb, mm, 64);
      }
      if (m16 == 0){
        int n = n0 + wv * 16 + g * 4 + jj;
        if (n < N){ aT[n * R + r] = pa; bT[n * R + r] = pb; }
      }
    }
  }
#pragma unroll
  for (int hf = 0; hf < 8; ++hf){
#pragma unroll
    for (int jj = 0; jj < 4; ++jj){
      ot[wv * 16 + g * 4 + jj][hf * 16 + m16] = f2bf(acc[hf][jj]);
    }
  }
  __syncthreads();
  unsigned short* dstp = xw + ((size_t)r * N + n0) * 128;
  int limit = (N - n0 < 64) ? (N - n0) * 16 : 1024;
  for (int i = threadIdx.x; i < limit; i += 256){
    int row = i >> 4, c16 = i & 15;
    *(uint4*)(dstp + row * 128 + c16 * 8) = *(const uint4*)&ot[row][c16 * 8];
  }
}

// ---- segment softmax, 2 sweeps; normalization factored into denom[n].
//      pass1: one random bT gather/edge, store raw logit to alp, track max.
//      pass2: STREAMING alp re-read, exp, sum; store e; denom = 1/sum. ----
__global__ __launch_bounds__(256) void k_alpha(const int* __restrict__ rp,
    const int* __restrict__ pack, const float* __restrict__ aT, const float* __restrict__ bT,
    float* __restrict__ alp, float* __restrict__ denom, int N, int R){
  int wv = threadIdx.x >> 6, ln = threadIdx.x & 63;
  int n = blockIdx.x * 4 + wv;
  if (n >= N) return;
  int beg = rp[n * R], end = rp[n * R + R];
  if (end <= beg) return;
  float mx = -3.4e38f;
  for (int i = beg + ln; i < end; i += 64){
    int v = pack[i]; int t = v >> 27; int s = v & 0x7ffffff;
    float l = aT[n * R + t] + bT[s * R + t];   // aT line is L1-hot per node
    l = l > 0.f ? l : 0.2f * l;
    alp[i] = l;
    mx = fmaxf(mx, l);
  }
  mx = wred_max(mx);
  float sm = 0.f;
  for (int i = beg + ln; i < end; i += 64){
    float ev = __expf(alp[i] - mx);
    alp[i] = ev; sm += ev;
  }
  sm = wred_sum(sm);
  if (ln == 0) denom[n] = 1.f / sm;
}

// ---- aggregation: wave/node, 4-wide unroll, xw[R][N][128] gathers;
//      epilogue: *denom, +bias, relu -> x bf16 ----
__global__ __launch_bounds__(256) void k_aggX(const unsigned short* __restrict__ xw,
    const int* __restrict__ rp, const int* __restrict__ pack, const float* __restrict__ alp,
    const float* __restrict__ denom, const float* __restrict__ bias,
    unsigned short* __restrict__ xo, int N, int R){
  int wv = threadIdx.x >> 6, ln = threadIdx.x & 63;
  int n = blockIdx.x * 4 + wv;
  if (n >= N) return;
  int beg = rp[n * R], end = rp[n * R + R];
  float2 s0 = {0.f, 0.f}, s1 = {0.f, 0.f}, s2 = {0.f, 0.f}, s3 = {0.f, 0.f};
  int i = beg;
  for (; i + 3 < end; i += 4){
    int v0 = pack[i], v1 = pack[i + 1], v2 = pack[i + 2], v3 = pack[i + 3];
    float al0 = alp[i], al1 = alp[i + 1], al2 = alp[i + 2], al3 = alp[i + 3];
    unsigned u0 = *(const unsigned*)(xw + ((size_t)(v0 >> 27) * N + (v0 & 0x7ffffff)) * 128 + 2 * ln);
    unsigned u1 = *(const unsigned*)(xw + ((size_t)(v1 >> 27) * N + (v1 & 0x7ffffff)) * 128 + 2 * ln);
    unsigned u2 = *(const unsigned*)(xw + ((size_t)(v2 >> 27) * N + (v2 & 0x7ffffff)) * 128 + 2 * ln);
    unsigned u3 = *(const unsigned*)(xw + ((size_t)(v3 >> 27) * N + (v3 & 0x7ffffff)) * 128 + 2 * ln);
    s0.x += al0 * __uint_as_float(u0 << 16);
    s0.y += al0 * __uint_as_float(u0 & 0xffff0000u);
    s1.x += al1 * __uint_as_float(u1 << 16);
    s1.y += al1 * __uint_as_float(u1 & 0xffff0000u);
    s2.x += al2 * __uint_as_float(u2 << 16);
    s2.y += al2 * __uint_as_float(u2 & 0xffff0000u);
    s3.x += al3 * __uint_as_float(u3 << 16);
    s3.y += al3 * __uint_as_float(u3 & 0xffff0000u);
  }
  for (; i < end; ++i){
    int v0 = pack[i];
    float al0 = alp[i];
    unsigned u0 = *(const unsigned*)(xw + ((size_t)(v0 >> 27) * N + (v0 & 0x7ffffff)) * 128 + 2 * ln);
    s0.x += al0 * __uint_as_float(u0 << 16);
    s0.y += al0 * __uint_as_float(u0 & 0xffff0000u);
  }
  float dn = (end > beg) ? denom[n] : 0.f;
  float ox = fmaxf((s0.x + s1.x + s2.x + s3.x) * dn + bias[2 * ln], 0.f);
  float oy = fmaxf((s0.y + s1.y + s2.y + s3.y) * dn + bias[2 * ln + 1], 0.f);
  unsigned u = ((unsigned)f2bf(oy) << 16) | f2bf(ox);
  *(unsigned*)(xo + (size_t)n * D + 2 * ln) = u;
}

// ---- final linear + per-graph segment sum (sorted-run LDS reduce) ----
__global__ __launch_bounds__(256) void k_final(const unsigned short* __restrict__ x,
    const unsigned short* __restrict__ lwbf, const float* __restrict__ lb,
    const int* __restrict__ batch, float* __restrict__ out, int N){
  __shared__ unsigned short wt[128][136];
  __shared__ float st[64][129];
  __shared__ int bsh[64];
  {
    const uint4* src = (const uint4*)lwbf;
    for (int i = threadIdx.x; i < 2048; i += 256){
      int h = i >> 4, kblk = i & 15;
      *(uint4*)&wt[h][kblk * 8] = src[i];
    }
  }
  __syncthreads();
  int wv = threadIdx.x >> 6, ln = threadIdx.x & 63;
  int g = ln >> 4, m16 = ln & 15;
  int n0 = blockIdx.x * 64;
  int nA = n0 + wv * 16 + m16;
  f32x4 acc[8];
#pragma unroll
  for (int i = 0; i < 8; ++i) acc[i] = (f32x4){0.f, 0.f, 0.f, 0.f};
#pragma unroll
  for (int kc = 0; kc < 4; ++kc){
    bf16x8 af = (bf16x8){0,0,0,0,0,0,0,0};
    if (nA < N) af = *(const bf16x8*)(x + (size_t)nA * D + kc * 32 + g * 8);
#pragma unroll
    for (int hf = 0; hf < 8; ++hf){
      bf16x8 bfr = *(const bf16x8*)&wt[hf * 16 + m16][kc * 32 + g * 8];
      acc[hf] = __builtin_amdgcn_mfma_f32_16x16x32_bf16(af, bfr, acc[hf], 0, 0, 0);
    }
  }
#pragma unroll
  for (int hf = 0; hf < 8; ++hf){
    int h = hf * 16 + m16;
    float bv = lb[h];
#pragma unroll
    for (int jj = 0; jj < 4; ++jj){
      int row = wv * 16 + g * 4 + jj;
      int n = n0 + row;
      st[row][h] = (n < N) ? (acc[hf][jj] + bv) : 0.f;
    }
  }
  if (threadIdx.x < 64){
    int n = n0 + threadIdx.x;
    bsh[threadIdx.x] = (n < N) ? batch[n] : -1;
  }
  __syncthreads();
  if (threadIdx.x < 128){
    int h = threadIdx.x;
    int lastValid = (N - n0 < 64) ? (N - n0 - 1) : 63;
    int cg = bsh[0];
    float sum = 0.f;
    for (int row = 0; row <= lastValid; ++row){
      int bg = bsh[row];
      if (bg != cg){
        atomicAdd(&out[(size_t)cg * D + h], sum);
        sum = 0.f; cg = bg;
      }
      sum += st[row][h];
    }
    atomicAdd(&out[(size_t)cg * D + h], sum);
  }
}

extern "C" void kernel_launch(void* const* d_in, const int* in_sizes, int n_in,
                              void* d_out, int out_size, void* d_ws, size_t ws_size,
                              hipStream_t stream){
  const int*   xpad  = (const int*)d_in[0];
  const int*   eidx  = (const int*)d_in[1];
  const int*   etyp  = (const int*)d_in[2];
  const int*   batch = (const int*)d_in[3];
  const float* emb   = (const float*)d_in[4];
  const float* w1    = (const float*)d_in[5];
  const float* q1    = (const float*)d_in[6];
  const float* k1    = (const float*)d_in[7];
  const float* b1    = (const float*)d_in[8];
  const float* w2    = (const float*)d_in[9];
  const float* q2    = (const float*)d_in[10];
  const float* k2    = (const float*)d_in[11];
  const float* b2    = (const float*)d_in[12];
  const float* lw    = (const float*)d_in[13];
  const float* lb    = (const float*)d_in[14];

  int N = in_sizes[3];
  int M = in_sizes[0] / N;
  int E = in_sizes[2];
  int R = in_sizes[5] / (128 * 128);
  int NB = N * R;
  const int* esrc = eidx;
  const int* edst = eidx + E;

  char* p = (char*)d_ws;
  auto carve = [&](size_t b) -> void* {
    void* q = (void*)p; p += (b + 255) & ~(size_t)255; return q;
  };
  unsigned short* x_a = (unsigned short*)carve((size_t)N * D * 2);  // bf16
  unsigned short* x_b = (unsigned short*)carve((size_t)N * D * 2);  // bf16
  float* aT   = (float*)carve((size_t)N * R * 4);
  float* bT   = (float*)carve((size_t)N * R * 4);
  float* dnm  = (float*)carve((size_t)N * 4);
  int*   rp   = (int*)carve((size_t)(NB + 1) * 4);
  int*   cur  = (int*)carve((size_t)NB * 4);
  int*   pack = (int*)carve((size_t)E * 4);
  float* alp  = (float*)carve((size_t)E * 4);
  unsigned short* wbf1 = (unsigned short*)carve((size_t)R * 128 * 128 * 2);
  unsigned short* wbf2 = (unsigned short*)carve((size_t)R * 128 * 128 * 2);
  unsigned short* lwbf = (unsigned short*)carve((size_t)128 * 128 * 2);
  int* bsum = (int*)carve((size_t)4096 * 4);
  int* boff = (int*)carve((size_t)4096 * 4);
  if ((size_t)(p - (char*)d_ws) > ws_size) return;
  unsigned short* xw = (unsigned short*)carve((size_t)N * R * 128 * 2);
  if ((size_t)(p - (char*)d_ws) > ws_size) return;  // xw is required in this version

  hipMemsetAsync(cur, 0, (size_t)NB * 4, stream);
  hipMemsetAsync(d_out, 0, (size_t)out_size * 4, stream);

  int eg = (E + 255) / 256;
  int nblk = (NB + 1023) / 1024;
  k_count   <<<eg, 256, 0, stream>>>(edst, etyp, cur, E, R);
  k_scan_blk<<<nblk, 256, 0, stream>>>(cur, bsum, NB);
  k_scan_top<<<1, 1024, 0, stream>>>(bsum, boff, rp, nblk, NB);
  k_scan_fin<<<nblk, 256, 0, stream>>>(cur, boff, rp, NB);
  k_scatter <<<eg, 256, 0, stream>>>(esrc, edst, etyp, cur, pack, E, R);

  int wtot = R * 128 * 128;
  k_wtr<<<(wtot + 255) / 256, 256, 0, stream>>>(w1, wbf1, wtot);
  k_wtr<<<(wtot + 255) / 256, 256, 0, stream>>>(w2, wbf2, wtot);
  k_cvt<<<(128 * 128 + 255) / 256, 256, 0, stream>>>(lw, lwbf, 128 * 128);

  int ng4 = (N + 3) / 4;
  int ntile = (N + 63) / 64;
  int nwg = ntile * R;
  k_pool<<<ng4, 256, 0, stream>>>(xpad, emb, x_a, N, M);

  // layer 1
  k_xw   <<<nwg, 256, 0, stream>>>(x_a, wbf1, q1, k1, xw, aT, bT, N, R, nwg);
  k_alpha<<<ng4, 256, 0, stream>>>(rp, pack, aT, bT, alp, dnm, N, R);
  k_aggX <<<ng4, 256, 0, stream>>>(xw, rp, pack, alp, dnm, b1, x_b, N, R);

  // layer 2
  k_xw   <<<nwg, 256, 0, stream>>>(x_b, wbf2, q2, k2, xw, aT, bT, N, R, nwg);
  k_alpha<<<ng4, 256, 0, stream>>>(rp, pack, aT, bT, alp, dnm, N, R);
  k_aggX <<<ng4, 256, 0, stream>>>(xw, rp, pack, alp, dnm, b2, x_a, N, R);

  // final linear + graph segment-sum
  k_final<<<ntile, 256, 0, stream>>>(x_a, lwbf, lb, batch, (float*)d_out, N);
}

// Round 12
// 352.845 us; speedup vs baseline: 1.8063x; 1.3570x over previous
//
#include <hip/hip_runtime.h>
#include <hip/hip_bf16.h>
#include <math.h>

#define D 128

typedef __attribute__((ext_vector_type(4))) float f32x4;
typedef __attribute__((ext_vector_type(8))) short bf16x8;

__device__ inline unsigned short f2bf(float f){
  unsigned u = __float_as_uint(f);
  u += 0x7fffu + ((u >> 16) & 1u);
  return (unsigned short)(u >> 16);
}
__device__ inline float wred_sum(float v){
#pragma unroll
  for (int m = 1; m < 64; m <<= 1) v += __shfl_xor(v, m, 64);
  return v;
}
__device__ inline float wred_max(float v){
#pragma unroll
  for (int m = 1; m < 64; m <<= 1) v = fmaxf(v, __shfl_xor(v, m, 64));
  return v;
}

// ---- embedding mean-pool: wave per node -> x bf16 ----
__global__ __launch_bounds__(256) void k_pool(const int* __restrict__ xpad,
    const float* __restrict__ emb, unsigned short* __restrict__ xo, int N, int M){
  int wv = threadIdx.x >> 6, ln = threadIdx.x & 63;
  int n = blockIdx.x * 4 + wv;
  if (n >= N) return;
  const int4* xr = (const int4*)(xpad + n * M);
  int4 ia = xr[0], ib = xr[1];
  int cnt = (ia.x >= 0) + (ia.y >= 0) + (ia.z >= 0) + (ia.w >= 0)
          + (ib.x >= 0) + (ib.y >= 0) + (ib.z >= 0) + (ib.w >= 0);
  float2 acc = {0.f, 0.f};
  int m = 0;
  for (; m + 1 < cnt; m += 2){
    int i0 = xpad[n * M + m], i1 = xpad[n * M + m + 1];
    float2 v0 = ((const float2*)(emb + (size_t)i0 * D))[ln];
    float2 v1 = ((const float2*)(emb + (size_t)i1 * D))[ln];
    acc.x += v0.x + v1.x; acc.y += v0.y + v1.y;
  }
  if (m < cnt){
    int i0 = xpad[n * M + m];
    float2 v0 = ((const float2*)(emb + (size_t)i0 * D))[ln];
    acc.x += v0.x; acc.y += v0.y;
  }
  float inv = 1.f / (float)cnt;
  unsigned u = ((unsigned)f2bf(acc.y * inv) << 16) | f2bf(acc.x * inv);
  *(unsigned*)(xo + (size_t)n * D + 2 * ln) = u;
}

// ---- CSR build over buckets (dst*R + et) ----
__global__ void k_count(const int* __restrict__ dst, const int* __restrict__ et,
                        int* __restrict__ cnt, int E, int R){
  int e = blockIdx.x * 256 + threadIdx.x;
  if (e < E) atomicAdd(&cnt[dst[e] * R + et[e]], 1);
}

__global__ __launch_bounds__(256) void k_scan_blk(const int* __restrict__ cc,
    int* __restrict__ bsum, int nb){
  __shared__ int sh[256];
  int base = blockIdx.x * 1024 + threadIdx.x * 4;
  int s = 0;
#pragma unroll
  for (int j = 0; j < 4; ++j){
    int i = base + j;
    if (i < nb) s += cc[i];
  }
  sh[threadIdx.x] = s; __syncthreads();
  for (int off = 128; off > 0; off >>= 1){
    if (threadIdx.x < off) sh[threadIdx.x] += sh[threadIdx.x + off];
    __syncthreads();
  }
  if (threadIdx.x == 0) bsum[blockIdx.x] = sh[0];
}

__global__ __launch_bounds__(1024) void k_scan_top(const int* __restrict__ bsum,
    int* __restrict__ boff, int* __restrict__ rp, int nblk, int nb){
  __shared__ int sh[1024];
  int t = threadIdx.x;
  int v = (t < nblk) ? bsum[t] : 0;
  sh[t] = v; __syncthreads();
  for (int off = 1; off < 1024; off <<= 1){
    int a = sh[t];
    int b = (t >= off) ? sh[t - off] : 0;
    __syncthreads();
    sh[t] = a + b;
    __syncthreads();
  }
  if (t < nblk) boff[t] = sh[t] - v;
  if (t == 1023) rp[nb] = sh[1023];
}

__global__ __launch_bounds__(256) void k_scan_fin(int* __restrict__ cc,
    const int* __restrict__ boff, int* __restrict__ rp, int nb){
  __shared__ int sh[256];
  int t = threadIdx.x;
  int base = blockIdx.x * 1024 + t * 4;
  int c[4]; int local = 0;
#pragma unroll
  for (int j = 0; j < 4; ++j){
    int i = base + j;
    c[j] = (i < nb) ? cc[i] : 0;
    local += c[j];
  }
  sh[t] = local; __syncthreads();
  for (int off = 1; off < 256; off <<= 1){
    int a = sh[t];
    int b = (t >= off) ? sh[t - off] : 0;
    __syncthreads();
    sh[t] = a + b;
    __syncthreads();
  }
  int run = sh[t] - local + boff[blockIdx.x];
#pragma unroll
  for (int j = 0; j < 4; ++j){
    int i = base + j;
    if (i < nb){ rp[i] = run; cc[i] = run; run += c[j]; }
  }
}

__global__ void k_scatter(const int* __restrict__ src, const int* __restrict__ dst,
    const int* __restrict__ et, int* __restrict__ cur, int* __restrict__ pack, int E, int R){
  int e = blockIdx.x * 256 + threadIdx.x;
  if (e < E){
    int t = et[e];
    int p = atomicAdd(&cur[dst[e] * R + t], 1);
    pack[p] = (t << 27) | src[e];
  }
}

// ---- w[r][d][h] fp32 -> wbf[r][h][d] bf16 (transposed) ----
__global__ void k_wtr(const float* __restrict__ w, unsigned short* __restrict__ wbf, int total){
  int id = blockIdx.x * 256 + threadIdx.x;
  if (id >= total) return;
  int d = id & 127, h = (id >> 7) & 127, r = id >> 14;
  wbf[id] = f2bf(w[(size_t)r * 16384 + d * 128 + h]);
}

__global__ void k_cvt(const float* __restrict__ s, unsigned short* __restrict__ dd, int total){
  int id = blockIdx.x * 256 + threadIdx.x;
  if (id < total) dd[id] = f2bf(s[id]);
}

// ---- xw[r][n][h] = (x[n] @ w[r])[h] bf16 via MFMA.
//      B-OPERAND STAGED IN LDS: R4-R11's invariant ~120us floor was ~200MB of
//      per-lane 256B-stride wbf reads (64 cache lines / load, L1 thrash across
//      waves). Coalesced 32KB LDS stage + ds_read fragments removes it.
//      One (tile,r)/block + XCD swizzle; fused a,b epilogue. ----
__global__ __launch_bounds__(256) void k_xw(const unsigned short* __restrict__ x,
    const unsigned short* __restrict__ wbf,  // [R][h][k] bf16
    const float* __restrict__ qv, const float* __restrict__ kv,  // [128]
    unsigned short* __restrict__ xw,         // [R][N][128] bf16
    float* __restrict__ aT, float* __restrict__ bT,              // [N*R]
    int N, int R, int nwg){
  __shared__ unsigned short wt[128][136];    // w[r] [h][k], 272B rows
  __shared__ unsigned short ot[64][136];
  int wv = threadIdx.x >> 6, ln = threadIdx.x & 63;
  int g = ln >> 4, m16 = ln & 15;
  int orig = blockIdx.x;
  int q = nwg >> 3, rm = nwg & 7;
  int xcd = orig & 7, idx = orig >> 3;
  int wgid = (xcd < rm ? xcd * (q + 1) : rm * (q + 1) + (xcd - rm) * q) + idx;
  int r    = wgid % 8;
  int tile = wgid / 8;
  int n0 = tile * 64;
  int nA = n0 + wv * 16 + m16;
  // stage w[r] -> LDS, coalesced 16B (issue first so it overlaps x loads)
  {
    const uint4* wsrc = (const uint4*)(wbf + (size_t)r * 16384);
    for (int i = threadIdx.x; i < 2048; i += 256){
      int h = i >> 4, dblk = i & 15;
      *(uint4*)&wt[h][dblk * 8] = wsrc[i];
    }
  }
  bf16x8 af[4];
#pragma unroll
  for (int kc = 0; kc < 4; ++kc) af[kc] = (bf16x8){0,0,0,0,0,0,0,0};
  if (nA < N){
#pragma unroll
    for (int kc = 0; kc < 4; ++kc)
      af[kc] = *(const bf16x8*)(x + (size_t)nA * D + kc * 32 + g * 8);
  }
  __syncthreads();
  f32x4 acc[8];
#pragma unroll
  for (int i = 0; i < 8; ++i) acc[i] = (f32x4){0.f, 0.f, 0.f, 0.f};
#pragma unroll
  for (int kc = 0; kc < 4; ++kc){
#pragma unroll
    for (int hf = 0; hf < 8; ++hf){
      bf16x8 bfr = *(const bf16x8*)&wt[hf * 16 + m16][kc * 32 + g * 8];
      acc[hf] = __builtin_amdgcn_mfma_f32_16x16x32_bf16(af[kc], bfr, acc[hf], 0, 0, 0);
    }
  }
  // fused a,b: lane holds h = hf*16+m16 for rows (wv*16 + g*4 + jj)
  {
    float qr[8], kr[8];
#pragma unroll
    for (int hf = 0; hf < 8; ++hf){ qr[hf] = qv[hf * 16 + m16]; kr[hf] = kv[hf * 16 + m16]; }
#pragma unroll
    for (int jj = 0; jj < 4; ++jj){
      float pa = 0.f, pb = 0.f;
#pragma unroll
      for (int hf = 0; hf < 8; ++hf){
        pa += acc[hf][jj] * qr[hf];
        pb += acc[hf][jj] * kr[hf];
      }
#pragma unroll
      for (int mm = 1; mm < 16; mm <<= 1){
        pa += __shfl_xor(pa, mm, 64);
        pb += __shfl_xor(pb, mm, 64);
      }
      if (m16 == 0){
        int n = n0 + wv * 16 + g * 4 + jj;
        if (n < N){ aT[n * R + r] = pa; bT[n * R + r] = pb; }
      }
    }
  }
#pragma unroll
  for (int hf = 0; hf < 8; ++hf){
#pragma unroll
    for (int jj = 0; jj < 4; ++jj){
      ot[wv * 16 + g * 4 + jj][hf * 16 + m16] = f2bf(acc[hf][jj]);
    }
  }
  __syncthreads();
  unsigned short* dstp = xw + ((size_t)r * N + n0) * 128;
  int limit = (N - n0 < 64) ? (N - n0) * 16 : 1024;
  for (int i = threadIdx.x; i < limit; i += 256){
    int row = i >> 4, c16 = i & 15;
    *(uint4*)(dstp + row * 128 + c16 * 8) = *(const uint4*)&ot[row][c16 * 8];
  }
}

// ---- segment softmax, 2 sweeps; normalization factored into denom[n] ----
__global__ __launch_bounds__(256) void k_alpha(const int* __restrict__ rp,
    const int* __restrict__ pack, const float* __restrict__ aT, const float* __restrict__ bT,
    float* __restrict__ alp, float* __restrict__ denom, int N, int R){
  int wv = threadIdx.x >> 6, ln = threadIdx.x & 63;
  int n = blockIdx.x * 4 + wv;
  if (n >= N) return;
  int beg = rp[n * R], end = rp[n * R + R];
  if (end <= beg) return;
  float mx = -3.4e38f;
  for (int i = beg + ln; i < end; i += 64){
    int v = pack[i]; int t = v >> 27; int s = v & 0x7ffffff;
    float l = aT[n * R + t] + bT[s * R + t];
    l = l > 0.f ? l : 0.2f * l;
    alp[i] = l;
    mx = fmaxf(mx, l);
  }
  mx = wred_max(mx);
  float sm = 0.f;
  for (int i = beg + ln; i < end; i += 64){
    float ev = __expf(alp[i] - mx);
    alp[i] = ev; sm += ev;
  }
  sm = wred_sum(sm);
  if (ln == 0) denom[n] = 1.f / sm;
}

// ---- aggregation: wave/node, 4-wide unroll, xw[R][N][128] gathers ----
__global__ __launch_bounds__(256) void k_aggX(const unsigned short* __restrict__ xw,
    const int* __restrict__ rp, const int* __restrict__ pack, const float* __restrict__ alp,
    const float* __restrict__ denom, const float* __restrict__ bias,
    unsigned short* __restrict__ xo, int N, int R){
  int wv = threadIdx.x >> 6, ln = threadIdx.x & 63;
  int n = blockIdx.x * 4 + wv;
  if (n >= N) return;
  int beg = rp[n * R], end = rp[n * R + R];
  float2 s0 = {0.f, 0.f}, s1 = {0.f, 0.f}, s2 = {0.f, 0.f}, s3 = {0.f, 0.f};
  int i = beg;
  for (; i + 3 < end; i += 4){
    int v0 = pack[i], v1 = pack[i + 1], v2 = pack[i + 2], v3 = pack[i + 3];
    float al0 = alp[i], al1 = alp[i + 1], al2 = alp[i + 2], al3 = alp[i + 3];
    unsigned u0 = *(const unsigned*)(xw + ((size_t)(v0 >> 27) * N + (v0 & 0x7ffffff)) * 128 + 2 * ln);
    unsigned u1 = *(const unsigned*)(xw + ((size_t)(v1 >> 27) * N + (v1 & 0x7ffffff)) * 128 + 2 * ln);
    unsigned u2 = *(const unsigned*)(xw + ((size_t)(v2 >> 27) * N + (v2 & 0x7ffffff)) * 128 + 2 * ln);
    unsigned u3 = *(const unsigned*)(xw + ((size_t)(v3 >> 27) * N + (v3 & 0x7ffffff)) * 128 + 2 * ln);
    s0.x += al0 * __uint_as_float(u0 << 16);
    s0.y += al0 * __uint_as_float(u0 & 0xffff0000u);
    s1.x += al1 * __uint_as_float(u1 << 16);
    s1.y += al1 * __uint_as_float(u1 & 0xffff0000u);
    s2.x += al2 * __uint_as_float(u2 << 16);
    s2.y += al2 * __uint_as_float(u2 & 0xffff0000u);
    s3.x += al3 * __uint_as_float(u3 << 16);
    s3.y += al3 * __uint_as_float(u3 & 0xffff0000u);
  }
  for (; i < end; ++i){
    int v0 = pack[i];
    float al0 = alp[i];
    unsigned u0 = *(const unsigned*)(xw + ((size_t)(v0 >> 27) * N + (v0 & 0x7ffffff)) * 128 + 2 * ln);
    s0.x += al0 * __uint_as_float(u0 << 16);
    s0.y += al0 * __uint_as_float(u0 & 0xffff0000u);
  }
  float dn = (end > beg) ? denom[n] : 0.f;
  float ox = fmaxf((s0.x + s1.x + s2.x + s3.x) * dn + bias[2 * ln], 0.f);
  float oy = fmaxf((s0.y + s1.y + s2.y + s3.y) * dn + bias[2 * ln + 1], 0.f);
  unsigned u = ((unsigned)f2bf(oy) << 16) | f2bf(ox);
  *(unsigned*)(xo + (size_t)n * D + 2 * ln) = u;
}

// ---- final linear + per-graph segment sum (sorted-run LDS reduce) ----
__global__ __launch_bounds__(256) void k_final(const unsigned short* __restrict__ x,
    const unsigned short* __restrict__ lwbf, const float* __restrict__ lb,
    const int* __restrict__ batch, float* __restrict__ out, int N){
  __shared__ unsigned short wt[128][136];
  __shared__ float st[64][129];
  __shared__ int bsh[64];
  {
    const uint4* src = (const uint4*)lwbf;
    for (int i = threadIdx.x; i < 2048; i += 256){
      int h = i >> 4, kblk = i & 15;
      *(uint4*)&wt[h][kblk * 8] = src[i];
    }
  }
  __syncthreads();
  int wv = threadIdx.x >> 6, ln = threadIdx.x & 63;
  int g = ln >> 4, m16 = ln & 15;
  int n0 = blockIdx.x * 64;
  int nA = n0 + wv * 16 + m16;
  f32x4 acc[8];
#pragma unroll
  for (int i = 0; i < 8; ++i) acc[i] = (f32x4){0.f, 0.f, 0.f, 0.f};
#pragma unroll
  for (int kc = 0; kc < 4; ++kc){
    bf16x8 af = (bf16x8){0,0,0,0,0,0,0,0};
    if (nA < N) af = *(const bf16x8*)(x + (size_t)nA * D + kc * 32 + g * 8);
#pragma unroll
    for (int hf = 0; hf < 8; ++hf){
      bf16x8 bfr = *(const bf16x8*)&wt[hf * 16 + m16][kc * 32 + g * 8];
      acc[hf] = __builtin_amdgcn_mfma_f32_16x16x32_bf16(af, bfr, acc[hf], 0, 0, 0);
    }
  }
#pragma unroll
  for (int hf = 0; hf < 8; ++hf){
    int h = hf * 16 + m16;
    float bv = lb[h];
#pragma unroll
    for (int jj = 0; jj < 4; ++jj){
      int row = wv * 16 + g * 4 + jj;
      int n = n0 + row;
      st[row][h] = (n < N) ? (acc[hf][jj] + bv) : 0.f;
    }
  }
  if (threadIdx.x < 64){
    int n = n0 + threadIdx.x;
    bsh[threadIdx.x] = (n < N) ? batch[n] : -1;
  }
  __syncthreads();
  if (threadIdx.x < 128){
    int h = threadIdx.x;
    int lastValid = (N - n0 < 64) ? (N - n0 - 1) : 63;
    int cg = bsh[0];
    float sum = 0.f;
    for (int row = 0; row <= lastValid; ++row){
      int bg = bsh[row];
      if (bg != cg){
        atomicAdd(&out[(size_t)cg * D + h], sum);
        sum = 0.f; cg = bg;
      }
      sum += st[row][h];
    }
    atomicAdd(&out[(size_t)cg * D + h], sum);
  }
}

extern "C" void kernel_launch(void* const* d_in, const int* in_sizes, int n_in,
                              void* d_out, int out_size, void* d_ws, size_t ws_size,
                              hipStream_t stream){
  const int*   xpad  = (const int*)d_in[0];
  const int*   eidx  = (const int*)d_in[1];
  const int*   etyp  = (const int*)d_in[2];
  const int*   batch = (const int*)d_in[3];
  const float* emb   = (const float*)d_in[4];
  const float* w1    = (const float*)d_in[5];
  const float* q1    = (const float*)d_in[6];
  const float* k1    = (const float*)d_in[7];
  const float* b1    = (const float*)d_in[8];
  const float* w2    = (const float*)d_in[9];
  const float* q2    = (const float*)d_in[10];
  const float* k2    = (const float*)d_in[11];
  const float* b2    = (const float*)d_in[12];
  const float* lw    = (const float*)d_in[13];
  const float* lb    = (const float*)d_in[14];

  int N = in_sizes[3];
  int M = in_sizes[0] / N;
  int E = in_sizes[2];
  int R = in_sizes[5] / (128 * 128);
  int NB = N * R;
  const int* esrc = eidx;
  const int* edst = eidx + E;

  char* p = (char*)d_ws;
  auto carve = [&](size_t b) -> void* {
    void* q = (void*)p; p += (b + 255) & ~(size_t)255; return q;
  };
  unsigned short* x_a = (unsigned short*)carve((size_t)N * D * 2);
  unsigned short* x_b = (unsigned short*)carve((size_t)N * D * 2);
  float* aT   = (float*)carve((size_t)N * R * 4);
  float* bT   = (float*)carve((size_t)N * R * 4);
  float* dnm  = (float*)carve((size_t)N * 4);
  int*   rp   = (int*)carve((size_t)(NB + 1) * 4);
  int*   cur  = (int*)carve((size_t)NB * 4);
  int*   pack = (int*)carve((size_t)E * 4);
  float* alp  = (float*)carve((size_t)E * 4);
  unsigned short* wbf1 = (unsigned short*)carve((size_t)R * 128 * 128 * 2);
  unsigned short* wbf2 = (unsigned short*)carve((size_t)R * 128 * 128 * 2);
  unsigned short* lwbf = (unsigned short*)carve((size_t)128 * 128 * 2);
  int* bsum = (int*)carve((size_t)4096 * 4);
  int* boff = (int*)carve((size_t)4096 * 4);
  if ((size_t)(p - (char*)d_ws) > ws_size) return;
  unsigned short* xw = (unsigned short*)carve((size_t)N * R * 128 * 2);
  if ((size_t)(p - (char*)d_ws) > ws_size) return;

  hipMemsetAsync(cur, 0, (size_t)NB * 4, stream);
  hipMemsetAsync(d_out, 0, (size_t)out_size * 4, stream);

  int eg = (E + 255) / 256;
  int nblk = (NB + 1023) / 1024;
  k_count   <<<eg, 256, 0, stream>>>(edst, etyp, cur, E, R);
  k_scan_blk<<<nblk, 256, 0, stream>>>(cur, bsum, NB);
  k_scan_top<<<1, 1024, 0, stream>>>(bsum, boff, rp, nblk, NB);
  k_scan_fin<<<nblk, 256, 0, stream>>>(cur, boff, rp, NB);
  k_scatter <<<eg, 256, 0, stream>>>(esrc, edst, etyp, cur, pack, E, R);

  int wtot = R * 128 * 128;
  k_wtr<<<(wtot + 255) / 256, 256, 0, stream>>>(w1, wbf1, wtot);
  k_wtr<<<(wtot + 255) / 256, 256, 0, stream>>>(w2, wbf2, wtot);
  k_cvt<<<(128 * 128 + 255) / 256, 256, 0, stream>>>(lw, lwbf, 128 * 128);

  int ng4 = (N + 3) / 4;
  int ntile = (N + 63) / 64;
  int nwg = ntile * R;
  k_pool<<<ng4, 256, 0, stream>>>(xpad, emb, x_a, N, M);

  // layer 1
  k_xw   <<<nwg, 256, 0, stream>>>(x_a, wbf1, q1, k1, xw, aT, bT, N, R, nwg);
  k_alpha<<<ng4, 256, 0, stream>>>(rp, pack, aT, bT, alp, dnm, N, R);
  k_aggX <<<ng4, 256, 0, stream>>>(xw, rp, pack, alp, dnm, b1, x_b, N, R);

  // layer 2
  k_xw   <<<nwg, 256, 0, stream>>>(x_b, wbf2, q2, k2, xw, aT, bT, N, R, nwg);
  k_alpha<<<ng4, 256, 0, stream>>>(rp, pack, aT, bT, alp, dnm, N, R);
  k_aggX <<<ng4, 256, 0, stream>>>(xw, rp, pack, alp, dnm, b2, x_a, N, R);

  // final linear + graph segment-sum
  k_final<<<ntile, 256, 0, stream>>>(x_a, lwbf, lb, batch, (float*)d_out, N);
}

// Round 13
// 338.651 us; speedup vs baseline: 1.8820x; 1.0419x over previous
//
#include <hip/hip_runtime.h>
#include <hip/hip_bf16.h>
#include <math.h>

#define D 128

typedef __attribute__((ext_vector_type(4))) float f32x4;
typedef __attribute__((ext_vector_type(8))) short bf16x8;

__device__ inline unsigned short f2bf(float f){
  unsigned u = __float_as_uint(f);
  u += 0x7fffu + ((u >> 16) & 1u);
  return (unsigned short)(u >> 16);
}
__device__ inline float wred_sum(float v){
#pragma unroll
  for (int m = 1; m < 64; m <<= 1) v += __shfl_xor(v, m, 64);
  return v;
}
__device__ inline float wred_max(float v){
#pragma unroll
  for (int m = 1; m < 64; m <<= 1) v = fmaxf(v, __shfl_xor(v, m, 64));
  return v;
}

// ---- embedding mean-pool: wave per node -> x bf16; 8-wide predicated
//      unroll (indices kept in registers, all gathers in flight) ----
__global__ __launch_bounds__(256) void k_pool(const int* __restrict__ xpad,
    const float* __restrict__ emb, unsigned short* __restrict__ xo, int N, int M){
  int wv = threadIdx.x >> 6, ln = threadIdx.x & 63;
  int n = blockIdx.x * 4 + wv;
  if (n >= N) return;
  const int4* xr = (const int4*)(xpad + n * M);
  int4 ia = xr[0], ib = xr[1];
  int cnt = (ia.x >= 0) + (ia.y >= 0) + (ia.z >= 0) + (ia.w >= 0)
          + (ib.x >= 0) + (ib.y >= 0) + (ib.z >= 0) + (ib.w >= 0);
  float2 acc = {0.f, 0.f};
#define POOL_ONE(idx) if ((idx) >= 0){ \
    float2 v = ((const float2*)(emb + (size_t)(idx) * D))[ln]; \
    acc.x += v.x; acc.y += v.y; }
  POOL_ONE(ia.x) POOL_ONE(ia.y) POOL_ONE(ia.z) POOL_ONE(ia.w)
  POOL_ONE(ib.x) POOL_ONE(ib.y) POOL_ONE(ib.z) POOL_ONE(ib.w)
#undef POOL_ONE
  float inv = 1.f / (float)cnt;
  unsigned u = ((unsigned)f2bf(acc.y * inv) << 16) | f2bf(acc.x * inv);
  *(unsigned*)(xo + (size_t)n * D + 2 * ln) = u;
}

// ---- CSR build over buckets (dst*R + et) ----
__global__ void k_count(const int* __restrict__ dst, const int* __restrict__ et,
                        int* __restrict__ cnt, int E, int R){
  int e = blockIdx.x * 256 + threadIdx.x;
  if (e < E) atomicAdd(&cnt[dst[e] * R + et[e]], 1);
}

__global__ __launch_bounds__(256) void k_scan_blk(const int* __restrict__ cc,
    int* __restrict__ bsum, int nb){
  __shared__ int sh[256];
  int base = blockIdx.x * 1024 + threadIdx.x * 4;
  int s = 0;
#pragma unroll
  for (int j = 0; j < 4; ++j){
    int i = base + j;
    if (i < nb) s += cc[i];
  }
  sh[threadIdx.x] = s; __syncthreads();
  for (int off = 128; off > 0; off >>= 1){
    if (threadIdx.x < off) sh[threadIdx.x] += sh[threadIdx.x + off];
    __syncthreads();
  }
  if (threadIdx.x == 0) bsum[blockIdx.x] = sh[0];
}

__global__ __launch_bounds__(1024) void k_scan_top(const int* __restrict__ bsum,
    int* __restrict__ boff, int* __restrict__ rp, int nblk, int nb){
  __shared__ int sh[1024];
  int t = threadIdx.x;
  int v = (t < nblk) ? bsum[t] : 0;
  sh[t] = v; __syncthreads();
  for (int off = 1; off < 1024; off <<= 1){
    int a = sh[t];
    int b = (t >= off) ? sh[t - off] : 0;
    __syncthreads();
    sh[t] = a + b;
    __syncthreads();
  }
  if (t < nblk) boff[t] = sh[t] - v;
  if (t == 1023) rp[nb] = sh[1023];
}

__global__ __launch_bounds__(256) void k_scan_fin(int* __restrict__ cc,
    const int* __restrict__ boff, int* __restrict__ rp, int nb){
  __shared__ int sh[256];
  int t = threadIdx.x;
  int base = blockIdx.x * 1024 + t * 4;
  int c[4]; int local = 0;
#pragma unroll
  for (int j = 0; j < 4; ++j){
    int i = base + j;
    c[j] = (i < nb) ? cc[i] : 0;
    local += c[j];
  }
  sh[t] = local; __syncthreads();
  for (int off = 1; off < 256; off <<= 1){
    int a = sh[t];
    int b = (t >= off) ? sh[t - off] : 0;
    __syncthreads();
    sh[t] = a + b;
    __syncthreads();
  }
  int run = sh[t] - local + boff[blockIdx.x];
#pragma unroll
  for (int j = 0; j < 4; ++j){
    int i = base + j;
    if (i < nb){ rp[i] = run; cc[i] = run; run += c[j]; }
  }
}

__global__ void k_scatter(const int* __restrict__ src, const int* __restrict__ dst,
    const int* __restrict__ et, int* __restrict__ cur, int* __restrict__ pack, int E, int R){
  int e = blockIdx.x * 256 + threadIdx.x;
  if (e < E){
    int t = et[e];
    int p = atomicAdd(&cur[dst[e] * R + t], 1);
    pack[p] = (t << 27) | src[e];
  }
}

// ---- w[r][d][h] fp32 -> wbf[r][h][d] bf16 (transposed) ----
__global__ void k_wtr(const float* __restrict__ w, unsigned short* __restrict__ wbf, int total){
  int id = blockIdx.x * 256 + threadIdx.x;
  if (id >= total) return;
  int d = id & 127, h = (id >> 7) & 127, r = id >> 14;
  wbf[id] = f2bf(w[(size_t)r * 16384 + d * 128 + h]);
}

__global__ void k_cvt(const float* __restrict__ s, unsigned short* __restrict__ dd, int total){
  int id = blockIdx.x * 256 + threadIdx.x;
  if (id < total) dd[id] = f2bf(s[id]);
}

// ---- xw[r][n][h] = (x[n] @ w[r])[h] bf16 via MFMA.
//      LDS-staged B (R12: 117->54us). This round: (a) ot ALIASES wt ->
//      32KB LDS exactly -> 5 blocks/CU (was 3 at 52KB); (b) XOR chunk
//      swizzle (c^=h&15) on unpadded [128][128] wt. Extra barrier after
//      MFMA since ot overwrites wt. ----
__global__ __launch_bounds__(256) void k_xw(const unsigned short* __restrict__ x,
    const unsigned short* __restrict__ wbf,  // [R][h][k] bf16
    const float* __restrict__ qv, const float* __restrict__ kv,  // [128]
    unsigned short* __restrict__ xw,         // [R][N][128] bf16
    float* __restrict__ aT, float* __restrict__ bT,              // [N*R]
    int N, int R, int nwg){
  __shared__ __align__(16) char smem[32768];
  unsigned short (*wt)[128] = (unsigned short (*)[128])smem;   // [128][128] swizzled
  unsigned short (*ot)[136] = (unsigned short (*)[136])smem;   // [64][136], aliases wt
  int wv = threadIdx.x >> 6, ln = threadIdx.x & 63;
  int g = ln >> 4, m16 = ln & 15;
  int orig = blockIdx.x;
  int q = nwg >> 3, rm = nwg & 7;
  int xcd = orig & 7, idx = orig >> 3;
  int wgid = (xcd < rm ? xcd * (q + 1) : rm * (q + 1) + (xcd - rm) * q) + idx;
  int r    = wgid % 8;
  int tile = wgid / 8;
  int n0 = tile * 64;
  int nA = n0 + wv * 16 + m16;
  // stage w[r] -> LDS (coalesced 16B, XOR chunk swizzle)
  {
    const uint4* wsrc = (const uint4*)(wbf + (size_t)r * 16384);
    for (int i = threadIdx.x; i < 2048; i += 256){
      int h = i >> 4, c = i & 15;
      *(uint4*)&wt[h][(c ^ (h & 15)) * 8] = wsrc[i];
    }
  }
  bf16x8 af[4];
#pragma unroll
  for (int kc = 0; kc < 4; ++kc) af[kc] = (bf16x8){0,0,0,0,0,0,0,0};
  if (nA < N){
#pragma unroll
    for (int kc = 0; kc < 4; ++kc)
      af[kc] = *(const bf16x8*)(x + (size_t)nA * D + kc * 32 + g * 8);
  }
  __syncthreads();
  f32x4 acc[8];
#pragma unroll
  for (int i = 0; i < 8; ++i) acc[i] = (f32x4){0.f, 0.f, 0.f, 0.f};
#pragma unroll
  for (int kc = 0; kc < 4; ++kc){
#pragma unroll
    for (int hf = 0; hf < 8; ++hf){
      // row h = hf*16+m16; chunk (kc*4+g) swizzled by h&15 == m16
      bf16x8 bfr = *(const bf16x8*)&wt[hf * 16 + m16][((kc * 4 + g) ^ m16) * 8];
      acc[hf] = __builtin_amdgcn_mfma_f32_16x16x32_bf16(af[kc], bfr, acc[hf], 0, 0, 0);
    }
  }
  // fused a,b epilogue (registers only)
  {
    float qr[8], kr[8];
#pragma unroll
    for (int hf = 0; hf < 8; ++hf){ qr[hf] = qv[hf * 16 + m16]; kr[hf] = kv[hf * 16 + m16]; }
#pragma unroll
    for (int jj = 0; jj < 4; ++jj){
      float pa = 0.f, pb = 0.f;
#pragma unroll
      for (int hf = 0; hf < 8; ++hf){
        pa += acc[hf][jj] * qr[hf];
        pb += acc[hf][jj] * kr[hf];
      }
#pragma unroll
      for (int mm = 1; mm < 16; mm <<= 1){
        pa += __shfl_xor(pa, mm, 64);
        pb += __shfl_xor(pb, mm, 64);
      }
      if (m16 == 0){
        int n = n0 + wv * 16 + g * 4 + jj;
        if (n < N){ aT[n * R + r] = pa; bT[n * R + r] = pb; }
      }
    }
  }
  __syncthreads();   // all waves done reading wt before ot overwrites it
#pragma unroll
  for (int hf = 0; hf < 8; ++hf){
#pragma unroll
    for (int jj = 0; jj < 4; ++jj){
      ot[wv * 16 + g * 4 + jj][hf * 16 + m16] = f2bf(acc[hf][jj]);
    }
  }
  __syncthreads();
  unsigned short* dstp = xw + ((size_t)r * N + n0) * 128;
  int limit = (N - n0 < 64) ? (N - n0) * 16 : 1024;
  for (int i = threadIdx.x; i < limit; i += 256){
    int row = i >> 4, c16 = i & 15;
    *(uint4*)(dstp + row * 128 + c16 * 8) = *(const uint4*)&ot[row][c16 * 8];
  }
}

// ---- segment softmax, 2 sweeps; normalization factored into denom[n] ----
__global__ __launch_bounds__(256) void k_alpha(const int* __restrict__ rp,
    const int* __restrict__ pack, const float* __restrict__ aT, const float* __restrict__ bT,
    float* __restrict__ alp, float* __restrict__ denom, int N, int R){
  int wv = threadIdx.x >> 6, ln = threadIdx.x & 63;
  int n = blockIdx.x * 4 + wv;
  if (n >= N) return;
  int beg = rp[n * R], end = rp[n * R + R];
  if (end <= beg) return;
  float mx = -3.4e38f;
  for (int i = beg + ln; i < end; i += 64){
    int v = pack[i]; int t = v >> 27; int s = v & 0x7ffffff;
    float l = aT[n * R + t] + bT[s * R + t];
    l = l > 0.f ? l : 0.2f * l;
    alp[i] = l;
    mx = fmaxf(mx, l);
  }
  mx = wred_max(mx);
  float sm = 0.f;
  for (int i = beg + ln; i < end; i += 64){
    float ev = __expf(alp[i] - mx);
    alp[i] = ev; sm += ev;
  }
  sm = wred_sum(sm);
  if (ln == 0) denom[n] = 1.f / sm;
}

// ---- aggregation: wave/node, 4-wide unroll, xw[R][N][128] gathers ----
__global__ __launch_bounds__(256) void k_aggX(const unsigned short* __restrict__ xw,
    const int* __restrict__ rp, const int* __restrict__ pack, const float* __restrict__ alp,
    const float* __restrict__ denom, const float* __restrict__ bias,
    unsigned short* __restrict__ xo, int N, int R){
  int wv = threadIdx.x >> 6, ln = threadIdx.x & 63;
  int n = blockIdx.x * 4 + wv;
  if (n >= N) return;
  int beg = rp[n * R], end = rp[n * R + R];
  float2 s0 = {0.f, 0.f}, s1 = {0.f, 0.f}, s2 = {0.f, 0.f}, s3 = {0.f, 0.f};
  int i = beg;
  for (; i + 3 < end; i += 4){
    int v0 = pack[i], v1 = pack[i + 1], v2 = pack[i + 2], v3 = pack[i + 3];
    float al0 = alp[i], al1 = alp[i + 1], al2 = alp[i + 2], al3 = alp[i + 3];
    unsigned u0 = *(const unsigned*)(xw + ((size_t)(v0 >> 27) * N + (v0 & 0x7ffffff)) * 128 + 2 * ln);
    unsigned u1 = *(const unsigned*)(xw + ((size_t)(v1 >> 27) * N + (v1 & 0x7ffffff)) * 128 + 2 * ln);
    unsigned u2 = *(const unsigned*)(xw + ((size_t)(v2 >> 27) * N + (v2 & 0x7ffffff)) * 128 + 2 * ln);
    unsigned u3 = *(const unsigned*)(xw + ((size_t)(v3 >> 27) * N + (v3 & 0x7ffffff)) * 128 + 2 * ln);
    s0.x += al0 * __uint_as_float(u0 << 16);
    s0.y += al0 * __uint_as_float(u0 & 0xffff0000u);
    s1.x += al1 * __uint_as_float(u1 << 16);
    s1.y += al1 * __uint_as_float(u1 & 0xffff0000u);
    s2.x += al2 * __uint_as_float(u2 << 16);
    s2.y += al2 * __uint_as_float(u2 & 0xffff0000u);
    s3.x += al3 * __uint_as_float(u3 << 16);
    s3.y += al3 * __uint_as_float(u3 & 0xffff0000u);
  }
  for (; i < end; ++i){
    int v0 = pack[i];
    float al0 = alp[i];
    unsigned u0 = *(const unsigned*)(xw + ((size_t)(v0 >> 27) * N + (v0 & 0x7ffffff)) * 128 + 2 * ln);
    s0.x += al0 * __uint_as_float(u0 << 16);
    s0.y += al0 * __uint_as_float(u0 & 0xffff0000u);
  }
  float dn = (end > beg) ? denom[n] : 0.f;
  float ox = fmaxf((s0.x + s1.x + s2.x + s3.x) * dn + bias[2 * ln], 0.f);
  float oy = fmaxf((s0.y + s1.y + s2.y + s3.y) * dn + bias[2 * ln + 1], 0.f);
  unsigned u = ((unsigned)f2bf(oy) << 16) | f2bf(ox);
  *(unsigned*)(xo + (size_t)n * D + 2 * ln) = u;
}

// ---- final linear + per-graph segment sum (sorted-run LDS reduce) ----
__global__ __launch_bounds__(256) void k_final(const unsigned short* __restrict__ x,
    const unsigned short* __restrict__ lwbf, const float* __restrict__ lb,
    const int* __restrict__ batch, float* __restrict__ out, int N){
  __shared__ unsigned short wt[128][136];
  __shared__ float st[64][129];
  __shared__ int bsh[64];
  {
    const uint4* src = (const uint4*)lwbf;
    for (int i = threadIdx.x; i < 2048; i += 256){
      int h = i >> 4, kblk = i & 15;
      *(uint4*)&wt[h][kblk * 8] = src[i];
    }
  }
  __syncthreads();
  int wv = threadIdx.x >> 6, ln = threadIdx.x & 63;
  int g = ln >> 4, m16 = ln & 15;
  int n0 = blockIdx.x * 64;
  int nA = n0 + wv * 16 + m16;
  f32x4 acc[8];
#pragma unroll
  for (int i = 0; i < 8; ++i) acc[i] = (f32x4){0.f, 0.f, 0.f, 0.f};
#pragma unroll
  for (int kc = 0; kc < 4; ++kc){
    bf16x8 af = (bf16x8){0,0,0,0,0,0,0,0};
    if (nA < N) af = *(const bf16x8*)(x + (size_t)nA * D + kc * 32 + g * 8);
#pragma unroll
    for (int hf = 0; hf < 8; ++hf){
      bf16x8 bfr = *(const bf16x8*)&wt[hf * 16 + m16][kc * 32 + g * 8];
      acc[hf] = __builtin_amdgcn_mfma_f32_16x16x32_bf16(af, bfr, acc[hf], 0, 0, 0);
    }
  }
#pragma unroll
  for (int hf = 0; hf < 8; ++hf){
    int h = hf * 16 + m16;
    float bv = lb[h];
#pragma unroll
    for (int jj = 0; jj < 4; ++jj){
      int row = wv * 16 + g * 4 + jj;
      int n = n0 + row;
      st[row][h] = (n < N) ? (acc[hf][jj] + bv) : 0.f;
    }
  }
  if (threadIdx.x < 64){
    int n = n0 + threadIdx.x;
    bsh[threadIdx.x] = (n < N) ? batch[n] : -1;
  }
  __syncthreads();
  if (threadIdx.x < 128){
    int h = threadIdx.x;
    int lastValid = (N - n0 < 64) ? (N - n0 - 1) : 63;
    int cg = bsh[0];
    float sum = 0.f;
    for (int row = 0; row <= lastValid; ++row){
      int bg = bsh[row];
      if (bg != cg){
        atomicAdd(&out[(size_t)cg * D + h], sum);
        sum = 0.f; cg = bg;
      }
      sum += st[row][h];
    }
    atomicAdd(&out[(size_t)cg * D + h], sum);
  }
}

extern "C" void kernel_launch(void* const* d_in, const int* in_sizes, int n_in,
                              void* d_out, int out_size, void* d_ws, size_t ws_size,
                              hipStream_t stream){
  const int*   xpad  = (const int*)d_in[0];
  const int*   eidx  = (const int*)d_in[1];
  const int*   etyp  = (const int*)d_in[2];
  const int*   batch = (const int*)d_in[3];
  const float* emb   = (const float*)d_in[4];
  const float* w1    = (const float*)d_in[5];
  const float* q1    = (const float*)d_in[6];
  const float* k1    = (const float*)d_in[7];
  const float* b1    = (const float*)d_in[8];
  const float* w2    = (const float*)d_in[9];
  const float* q2    = (const float*)d_in[10];
  const float* k2    = (const float*)d_in[11];
  const float* b2    = (const float*)d_in[12];
  const float* lw    = (const float*)d_in[13];
  const float* lb    = (const float*)d_in[14];

  int N = in_sizes[3];
  int M = in_sizes[0] / N;
  int E = in_sizes[2];
  int R = in_sizes[5] / (128 * 128);
  int NB = N * R;
  const int* esrc = eidx;
  const int* edst = eidx + E;

  char* p = (char*)d_ws;
  auto carve = [&](size_t b) -> void* {
    void* q = (void*)p; p += (b + 255) & ~(size_t)255; return q;
  };
  unsigned short* x_a = (unsigned short*)carve((size_t)N * D * 2);
  unsigned short* x_b = (unsigned short*)carve((size_t)N * D * 2);
  float* aT   = (float*)carve((size_t)N * R * 4);
  float* bT   = (float*)carve((size_t)N * R * 4);
  float* dnm  = (float*)carve((size_t)N * 4);
  int*   rp   = (int*)carve((size_t)(NB + 1) * 4);
  int*   cur  = (int*)carve((size_t)NB * 4);
  int*   pack = (int*)carve((size_t)E * 4);
  float* alp  = (float*)carve((size_t)E * 4);
  unsigned short* wbf1 = (unsigned short*)carve((size_t)R * 128 * 128 * 2);
  unsigned short* wbf2 = (unsigned short*)carve((size_t)R * 128 * 128 * 2);
  unsigned short* lwbf = (unsigned short*)carve((size_t)128 * 128 * 2);
  int* bsum = (int*)carve((size_t)4096 * 4);
  int* boff = (int*)carve((size_t)4096 * 4);
  if ((size_t)(p - (char*)d_ws) > ws_size) return;
  unsigned short* xw = (unsigned short*)carve((size_t)N * R * 128 * 2);
  if ((size_t)(p - (char*)d_ws) > ws_size) return;

  hipMemsetAsync(cur, 0, (size_t)NB * 4, stream);
  hipMemsetAsync(d_out, 0, (size_t)out_size * 4, stream);

  int eg = (E + 255) / 256;
  int nblk = (NB + 1023) / 1024;
  k_count   <<<eg, 256, 0, stream>>>(edst, etyp, cur, E, R);
  k_scan_blk<<<nblk, 256, 0, stream>>>(cur, bsum, NB);
  k_scan_top<<<1, 1024, 0, stream>>>(bsum, boff, rp, nblk, NB);
  k_scan_fin<<<nblk, 256, 0, stream>>>(cur, boff, rp, NB);
  k_scatter <<<eg, 256, 0, stream>>>(esrc, edst, etyp, cur, pack, E, R);

  int wtot = R * 128 * 128;
  k_wtr<<<(wtot + 255) / 256, 256, 0, stream>>>(w1, wbf1, wtot);
  k_wtr<<<(wtot + 255) / 256, 256, 0, stream>>>(w2, wbf2, wtot);
  k_cvt<<<(128 * 128 + 255) / 256, 256, 0, stream>>>(lw, lwbf, 128 * 128);

  int ng4 = (N + 3) / 4;
  int ntile = (N + 63) / 64;
  int nwg = ntile * R;
  k_pool<<<ng4, 256, 0, stream>>>(xpad, emb, x_a, N, M);

  // layer 1
  k_xw   <<<nwg, 256, 0, stream>>>(x_a, wbf1, q1, k1, xw, aT, bT, N, R, nwg);
  k_alpha<<<ng4, 256, 0, stream>>>(rp, pack, aT, bT, alp, dnm, N, R);
  k_aggX <<<ng4, 256, 0, stream>>>(xw, rp, pack, alp, dnm, b1, x_b, N, R);

  // layer 2
  k_xw   <<<nwg, 256, 0, stream>>>(x_b, wbf2, q2, k2, xw, aT, bT, N, R, nwg);
  k_alpha<<<ng4, 256, 0, stream>>>(rp, pack, aT, bT, alp, dnm, N, R);
  k_aggX <<<ng4, 256, 0, stream>>>(xw, rp, pack, alp, dnm, b2, x_a, N, R);

  // final linear + graph segment-sum
  k_final<<<ntile, 256, 0, stream>>>(x_a, lwbf, lb, batch, (float*)d_out, N);
}